// Round 4
// baseline (74.812 us; speedup 1.0000x reference)
//
#include <hip/hip_runtime.h>
#include <math.h>

// CustomCombinedLoss: weighted-sum BCE over positive_prob + MultiMarginLoss(p=1, margin=0.5).
// B=16384 rows, C=2048 classes, f32. Pure streaming reduction over 134.2 MB -> HBM-read-bound.
// hinge identity: sum_{j!=y} max(0, m - x[y] + x[j]) = sum_all_j max(0, c + x[j]) - 0.5, c = 0.5 - x[y].
//
// Single fused compute dispatch: per-block partials + "last block reduces".
// The arrival counter is reset to 0 by an async 4-byte memset node captured in the
// same graph, so `old == NBLK-1` identifies the true last arrival on the first call
// AND on every replay (round-3 lesson: without the reset, the firing block is NOT
// the last arrival and reads unwritten partials).

#define BN   16384
#define CN   2048
#define NBLK 2048
#define NTHR 256
#define RPB  (BN / NBLK)   // 8 contiguous rows per block

__global__ __launch_bounds__(NTHR) void loss_fused_kernel(
    const float* __restrict__ pp,       // [B] positive_prob
    const float* __restrict__ pred,     // [B*C] predictions
    const int*   __restrict__ tgt,      // [B] target in [0, C]
    float*        partial,              // [NBLK] per-block partials (d_ws)
    unsigned int* counter,              // arrival counter (d_ws, memset to 0 pre-launch)
    float*        out)                  // [1] loss
{
    const int tid  = threadIdx.x;
    const int row0 = blockIdx.x * RPB;

    float acc_h = 0.f;   // hinge terms (scaled by 1/C at the end)
    float acc_o = 0.f;   // BCE terms + per-row corrections

    #pragma unroll
    for (int r = 0; r < RPB; ++r) {
        const int row = row0 + r;
        const float* rowp = pred + (size_t)row * CN;
        const float4* rp4 = (const float4*)rowp;

        // issue row loads unconditionally — no dependence on tgt
        const float4 a = rp4[tid];
        const float4 b = rp4[tid + NTHR];

        const int   t = tgt[row];
        const float m = (t != 0) ? 1.0f : 0.0f;
        const int   y = (t > 0) ? (t - 1) : 0;
        const float xy = rowp[y];            // uniform per block -> broadcast
        const float c  = 0.5f - xy;          // margin - x[y]

        float h = fmaxf(0.f, c + a.x) + fmaxf(0.f, c + a.y)
                + fmaxf(0.f, c + a.z) + fmaxf(0.f, c + a.w)
                + fmaxf(0.f, c + b.x) + fmaxf(0.f, c + b.y)
                + fmaxf(0.f, c + b.z) + fmaxf(0.f, c + b.w);
        acc_h += m * h;

        if (tid == 0) {
            // remove the j==y hinge term: max(0, margin) = 0.5 (only when t != 0)
            acc_h -= m * 0.5f;
            // BCE: positive (t!=0): -max(log p, -100); negative: -2*max(log1p(-p), -100)
            const float p = pp[row];
            const float lp  = fmaxf(logf(p),    -100.f);
            const float l1p = fmaxf(log1pf(-p), -100.f);
            acc_o -= (t != 0) ? lp : 2.0f * l1p;
        }
    }

    float acc = acc_h * (1.0f / CN) + acc_o;

    // deterministic block reduce: wave64 shuffle tree, then LDS across 4 waves
    #pragma unroll
    for (int off = 32; off > 0; off >>= 1)
        acc += __shfl_down(acc, off, 64);
    __shared__ float sm[NTHR / 64];
    __shared__ int amLast;
    if ((tid & 63) == 0) sm[tid >> 6] = acc;
    __syncthreads();
    if (tid == 0) {
        float s = 0.f;
        #pragma unroll
        for (int i = 0; i < NTHR / 64; ++i) s += sm[i];
        partial[blockIdx.x] = s;
        __threadfence();                              // release: partial visible before count
        unsigned int old = atomicAdd(counter, 1u);    // device-scope on CDNA
        amLast = (old == (unsigned int)(NBLK - 1));   // counter reset to 0 each launch
    }
    __syncthreads();

    if (amLast) {
        __threadfence();                              // acquire: all partial writes visible
        // 2048 partials = 512 float4; 256 threads -> 2 float4 each, fixed order
        const float4* p4 = (const float4*)partial;
        const float4 a = p4[tid];
        const float4 b = p4[tid + NTHR];
        float f = (a.x + a.y) + (a.z + a.w) + (b.x + b.y) + (b.z + b.w);
        #pragma unroll
        for (int off = 32; off > 0; off >>= 1)
            f += __shfl_down(f, off, 64);
        if ((tid & 63) == 0) sm[tid >> 6] = f;
        __syncthreads();
        if (tid == 0) {
            float s = 0.f;
            #pragma unroll
            for (int i = 0; i < NTHR / 64; ++i) s += sm[i];
            out[0] = s;
        }
    }
}

extern "C" void kernel_launch(void* const* d_in, const int* in_sizes, int n_in,
                              void* d_out, int out_size, void* d_ws, size_t ws_size,
                              hipStream_t stream) {
    const float* pp   = (const float*)d_in[0];   // positive_prob [B]
    const float* pred = (const float*)d_in[1];   // predictions  [B, C]
    const int*   tgt  = (const int*)d_in[2];     // target       [B]
    float* out = (float*)d_out;

    // d_ws layout: [0, 256B) counter (only 4B used); [256B, 256B + NBLK*4) partials
    unsigned int* counter = (unsigned int*)d_ws;
    float* partial = (float*)((char*)d_ws + 256);

    // reset arrival counter every launch (graph-capturable async memset node)
    hipMemsetAsync(counter, 0, sizeof(unsigned int), stream);
    loss_fused_kernel<<<NBLK, NTHR, 0, stream>>>(pp, pred, tgt, partial, counter, out);
}

// Round 5
// 28.867 us; speedup vs baseline: 2.5916x; 2.5916x over previous
//
#include <hip/hip_runtime.h>
#include <math.h>

// CustomCombinedLoss: weighted-sum BCE over positive_prob + MultiMarginLoss(p=1, margin=0.5).
// B=16384 rows, C=2048 classes, f32. Pure streaming reduction over 134.2 MB -> HBM-read-bound.
// hinge identity: sum_{j!=y} max(0, m - x[y] + x[j]) = sum_all_j max(0, c + x[j]) - 0.5, c = 0.5 - x[y].
//
// Round-4 lesson: single-dispatch fusion via counter+fences costs ~100us (2048 agent-scope
// fences + same-address atomics across 8 non-coherent XCD L2s). Two dispatches (~4us extra)
// is the cheap cross-block sync on CDNA4. This round: two-kernel structure, with all
// dependent loads (tgt, x[y]) hoisted ahead of the 16 streaming float4 loads per block.

#define BN   16384
#define CN   2048
#define NBLK 2048
#define NTHR 256
#define RPB  (BN / NBLK)   // 8 contiguous rows per block

__global__ __launch_bounds__(NTHR) void loss_partial_kernel(
    const float* __restrict__ pp,     // [B] positive_prob
    const float* __restrict__ pred,   // [B*C] predictions
    const int*   __restrict__ tgt,    // [B] target in [0, C]
    float* __restrict__ partial)      // [NBLK] per-block partial sums
{
    const int tid  = threadIdx.x;
    const int row0 = blockIdx.x * RPB;

    // ---- hoist all target loads (row0 is 8-aligned -> 32B-aligned int4 pair) ----
    const int4 t03 = ((const int4*)(tgt + row0))[0];
    const int4 t47 = ((const int4*)(tgt + row0))[1];
    int t[RPB] = { t03.x, t03.y, t03.z, t03.w, t47.x, t47.y, t47.z, t47.w };

    // ---- hoist the 8 x[y] broadcast loads (uniform per block, 1 txn each) ----
    float c[RPB];   // 0.5 - x[y]
    float m[RPB];   // 1.0 if t!=0 else 0.0
    #pragma unroll
    for (int r = 0; r < RPB; ++r) {
        const int y = (t[r] > 0) ? (t[r] - 1) : 0;
        const float xy = pred[(size_t)(row0 + r) * CN + y];
        m[r] = (t[r] != 0) ? 1.0f : 0.0f;
        c[r] = 0.5f - xy;
    }

    // ---- streaming phase: 16 independent float4 loads, no dependent chains ----
    float acc_h = 0.f;
    #pragma unroll
    for (int r = 0; r < RPB; ++r) {
        const float4* rp4 = (const float4*)(pred + (size_t)(row0 + r) * CN);
        const float4 a = rp4[tid];
        const float4 b = rp4[tid + NTHR];
        float h = fmaxf(0.f, c[r] + a.x) + fmaxf(0.f, c[r] + a.y)
                + fmaxf(0.f, c[r] + a.z) + fmaxf(0.f, c[r] + a.w)
                + fmaxf(0.f, c[r] + b.x) + fmaxf(0.f, c[r] + b.y)
                + fmaxf(0.f, c[r] + b.z) + fmaxf(0.f, c[r] + b.w);
        acc_h += m[r] * h;
    }

    float acc_o = 0.f;
    if (tid == 0) {
        #pragma unroll
        for (int r = 0; r < RPB; ++r) {
            // remove the j==y hinge term: max(0, margin) = 0.5 (only when t != 0)
            acc_h -= m[r] * 0.5f;
            // BCE: positive (t!=0): -max(log p, -100); negative: -2*max(log1p(-p), -100)
            const float p = pp[row0 + r];
            const float lp  = fmaxf(logf(p),    -100.f);
            const float l1p = fmaxf(log1pf(-p), -100.f);
            acc_o -= (t[r] != 0) ? lp : 2.0f * l1p;
        }
    }

    float acc = acc_h * (1.0f / CN) + acc_o;

    // deterministic block reduce: wave64 shuffle tree, then LDS across 4 waves
    #pragma unroll
    for (int off = 32; off > 0; off >>= 1)
        acc += __shfl_down(acc, off, 64);
    __shared__ float sm[NTHR / 64];
    if ((tid & 63) == 0) sm[tid >> 6] = acc;
    __syncthreads();
    if (tid == 0) {
        float s = 0.f;
        #pragma unroll
        for (int i = 0; i < NTHR / 64; ++i) s += sm[i];
        partial[blockIdx.x] = s;
    }
}

__global__ __launch_bounds__(NTHR) void loss_final_kernel(
    const float* __restrict__ partial, float* __restrict__ out)
{
    const int tid = threadIdx.x;
    // 2048 partials = 512 float4; 256 threads -> 2 float4 each, fixed order
    const float4* p4 = (const float4*)partial;
    const float4 a = p4[tid];
    const float4 b = p4[tid + NTHR];
    float acc = (a.x + a.y) + (a.z + a.w) + (b.x + b.y) + (b.z + b.w);
    #pragma unroll
    for (int off = 32; off > 0; off >>= 1)
        acc += __shfl_down(acc, off, 64);
    __shared__ float sm[NTHR / 64];
    if ((tid & 63) == 0) sm[tid >> 6] = acc;
    __syncthreads();
    if (tid == 0) {
        float s = 0.f;
        #pragma unroll
        for (int i = 0; i < NTHR / 64; ++i) s += sm[i];
        out[0] = s;
    }
}

extern "C" void kernel_launch(void* const* d_in, const int* in_sizes, int n_in,
                              void* d_out, int out_size, void* d_ws, size_t ws_size,
                              hipStream_t stream) {
    const float* pp   = (const float*)d_in[0];   // positive_prob [B]
    const float* pred = (const float*)d_in[1];   // predictions  [B, C]
    const int*   tgt  = (const int*)d_in[2];     // target       [B]
    float* out     = (float*)d_out;
    float* partial = (float*)d_ws;               // NBLK floats = 8 KB scratch

    loss_partial_kernel<<<NBLK, NTHR, 0, stream>>>(pp, pred, tgt, partial);
    loss_final_kernel<<<1, NTHR, 0, stream>>>(partial, out);
}

// Round 6
// 27.776 us; speedup vs baseline: 2.6934x; 1.0393x over previous
//
#include <hip/hip_runtime.h>
#include <math.h>

// CustomCombinedLoss: weighted-sum BCE over positive_prob + MultiMarginLoss(p=1, margin=0.5).
// B=16384 rows, C=2048 classes, f32. Pure streaming reduction over 134.2 MB -> HBM-read-bound.
// hinge identity: sum_{j!=y} max(0, m - x[y] + x[j]) = sum_all_j max(0, c + x[j]) - 0.5, c = 0.5 - x[y].
//
// Structure notes (measured):
//  - r4: single-dispatch fusion via counter+threadfence = ~100us sync cost (2048 agent-scope
//    fences + same-address atomic RMW across 8 non-coherent XCD L2s). Two dispatches win.
//  - r5: hoisting tgt/x[y] loads into a prologue HURT (27.6 -> 28.9us); the compiler already
//    schedules the streaming float4s independently. This file is the r2 schedule (best, 27.6us)
//    with a leaner single-wave finalizer.

#define BN   16384
#define CN   2048
#define NBLK 2048
#define NTHR 256
#define RPB  (BN / NBLK)   // 8 contiguous rows per block

__global__ __launch_bounds__(NTHR) void loss_partial_kernel(
    const float* __restrict__ pp,     // [B] positive_prob
    const float* __restrict__ pred,   // [B*C] predictions
    const int*   __restrict__ tgt,    // [B] target in [0, C]
    float* __restrict__ partial)      // [NBLK] per-block partial sums
{
    const int tid  = threadIdx.x;
    const int row0 = blockIdx.x * RPB;

    float acc_h = 0.f;   // hinge terms (scaled by 1/C at the end)
    float acc_o = 0.f;   // BCE terms + per-row corrections

    #pragma unroll
    for (int r = 0; r < RPB; ++r) {
        const int row = row0 + r;
        const float* rowp = pred + (size_t)row * CN;
        const float4* rp4 = (const float4*)rowp;

        // issue row loads unconditionally — no dependence on tgt
        const float4 a = rp4[tid];
        const float4 b = rp4[tid + NTHR];

        const int   t = tgt[row];
        const float m = (t != 0) ? 1.0f : 0.0f;
        const int   y = (t > 0) ? (t - 1) : 0;
        const float xy = rowp[y];            // uniform per block -> broadcast
        const float c  = 0.5f - xy;          // margin - x[y]

        float h = fmaxf(0.f, c + a.x) + fmaxf(0.f, c + a.y)
                + fmaxf(0.f, c + a.z) + fmaxf(0.f, c + a.w)
                + fmaxf(0.f, c + b.x) + fmaxf(0.f, c + b.y)
                + fmaxf(0.f, c + b.z) + fmaxf(0.f, c + b.w);
        acc_h += m * h;

        if (tid == 0) {
            // remove the j==y hinge term: max(0, margin) = 0.5 (only when t != 0)
            acc_h -= m * 0.5f;
            // BCE: positive (t!=0): -max(log p, -100); negative: -2*max(log1p(-p), -100)
            const float p = pp[row];
            const float lp  = fmaxf(logf(p),    -100.f);
            const float l1p = fmaxf(log1pf(-p), -100.f);
            acc_o -= (t != 0) ? lp : 2.0f * l1p;
        }
    }

    float acc = acc_h * (1.0f / CN) + acc_o;

    // deterministic block reduce: wave64 shuffle tree, then LDS across 4 waves
    #pragma unroll
    for (int off = 32; off > 0; off >>= 1)
        acc += __shfl_down(acc, off, 64);
    __shared__ float sm[NTHR / 64];
    if ((tid & 63) == 0) sm[tid >> 6] = acc;
    __syncthreads();
    if (tid == 0) {
        float s = 0.f;
        #pragma unroll
        for (int i = 0; i < NTHR / 64; ++i) s += sm[i];
        partial[blockIdx.x] = s;
    }
}

// single-wave finalizer: 64 lanes x 8 float4 = 2048 floats, pure shuffle tree,
// no LDS / no __syncthreads -> minimal latency after the partial kernel.
__global__ __launch_bounds__(64) void loss_final_kernel(
    const float* __restrict__ partial, float* __restrict__ out)
{
    const int lane = threadIdx.x;
    const float4* p4 = (const float4*)partial;
    float acc = 0.f;
    #pragma unroll
    for (int i = 0; i < 8; ++i) {
        const float4 a = p4[lane + 64 * i];
        acc += (a.x + a.y) + (a.z + a.w);
    }
    #pragma unroll
    for (int off = 32; off > 0; off >>= 1)
        acc += __shfl_down(acc, off, 64);
    if (lane == 0) out[0] = acc;
}

extern "C" void kernel_launch(void* const* d_in, const int* in_sizes, int n_in,
                              void* d_out, int out_size, void* d_ws, size_t ws_size,
                              hipStream_t stream) {
    const float* pp   = (const float*)d_in[0];   // positive_prob [B]
    const float* pred = (const float*)d_in[1];   // predictions  [B, C]
    const int*   tgt  = (const int*)d_in[2];     // target       [B]
    float* out     = (float*)d_out;
    float* partial = (float*)d_ws;               // NBLK floats = 8 KB scratch

    loss_partial_kernel<<<NBLK, NTHR, 0, stream>>>(pp, pred, tgt, partial);
    loss_final_kernel<<<1, 64, 0, stream>>>(partial, out);
}